// Round 3
// baseline (542.952 us; speedup 1.0000x reference)
//
#include <hip/hip_runtime.h>

typedef _Float16 h8 __attribute__((ext_vector_type(8)));
typedef _Float16 h4 __attribute__((ext_vector_type(4)));
typedef float f4 __attribute__((ext_vector_type(4)));

#define MFMA16(a, b, c) __builtin_amdgcn_mfma_f32_16x16x32_f16((a), (b), (c), 0, 0, 0)
#define AS1 __attribute__((address_space(1)))
#define AS3 __attribute__((address_space(3)))

static __device__ __forceinline__ void load_lds16(const _Float16* g, _Float16* l) {
  // 16B per lane, LDS dest = wave-uniform base + lane*16 [m97]
  __builtin_amdgcn_global_load_lds((const AS1 void*)g, (AS3 void*)l, 16, 0, 0);
}

// ---------------- fp32 -> fp16 elementwise convert ----------------
__global__ __launch_bounds__(256) void cvt_f32_f16(const float* __restrict__ in,
                                                   _Float16* __restrict__ out, int n) {
  int i = (blockIdx.x * 256 + threadIdx.x) * 4;
  if (i < n) {
    const float4 v = *(const float4*)(in + i);
    h4 o;
    o[0] = (_Float16)v.x; o[1] = (_Float16)v.y; o[2] = (_Float16)v.z; o[3] = (_Float16)v.w;
    *(h4*)(out + i) = o;
  }
}

// ---------------- transpose+convert: W[K][N] f32 -> Wt[N][K] f16 ----------------
__global__ __launch_bounds__(256) void transpose_cvt(const float* __restrict__ W,
                                                     _Float16* __restrict__ Wt, int K, int N) {
  __shared__ _Float16 t[64][66];
  int n0 = blockIdx.x * 64, k0 = blockIdx.y * 64;
  int c = threadIdx.x & 63, r0 = threadIdx.x >> 6;
  for (int i = 0; i < 16; i++) {
    int r = r0 * 16 + i;
    t[r][c] = (_Float16)W[(size_t)(k0 + r) * N + n0 + c];
  }
  __syncthreads();
  for (int i = 0; i < 16; i++) {
    int r = r0 * 16 + i;
    Wt[(size_t)(n0 + r) * K + k0 + c] = t[c][r];
  }
}

// ---------------- GEMM (BK=64): C[M][N] = A[M][K] @ Bt[N][K]^T + bias ----------------
// global_load_lds width=16 into unpadded BK=64 LDS, XOR chunk swizzle (8 chunks/row):
//   staging slot s: row r=s>>3, logical chunk = (s&7) ^ (r&7); with s = w*256+i*64+lane this
//   reduces to lc = (lane&7)^(lane>>3), r = w*32+i*8+(lane>>3) (uniform across i,w).
//   frag read: phys chunk = (ks*4+quad) ^ (l16&7) -> exact 8-phase b128 minimum, 0 conflicts.
// 32 MFMA per barrier (AITER ratio, s02). MODE 0: QKV scatter epilogue; MODE 1: fp32 out.
template <int MODE>
__global__ __launch_bounds__(256) void gemm_bt(const _Float16* __restrict__ A,
                                               const _Float16* __restrict__ Bt,
                                               const float* __restrict__ bias, int K,
                                               _Float16* __restrict__ qp, _Float16* __restrict__ kp,
                                               _Float16* __restrict__ vtp, float* __restrict__ outp,
                                               int N) {
  __shared__ _Float16 As[128 * 64];  // 16 KB each
  __shared__ _Float16 Bs[128 * 64];
  const int m0 = blockIdx.y * 128, n0 = blockIdx.x * 128;
  const int tid = threadIdx.x;
  const int w = tid >> 6, lane = tid & 63, quad = lane >> 4, l16 = lane & 15;
  const int wm = (w >> 1) * 64, wn = (w & 1) * 64;

  const int lc8 = (((lane & 7) ^ (lane >> 3)) * 8);  // swizzled k-offset (elements)
  const int rb = w * 32 + (lane >> 3);               // staging row for call i: rb + i*8
  const _Float16* ap0 = A + (size_t)(m0 + rb) * K + lc8;
  const _Float16* bp0 = Bt + (size_t)(n0 + rb) * K + lc8;
  _Float16* lA = As + w * 2048;  // wave-uniform LDS bases; +i*512 per call
  _Float16* lB = Bs + w * 2048;

  f4 acc[4][4] = {};
  for (int k0 = 0; k0 < K; k0 += 64) {
    __syncthreads();  // previous iteration's fragment reads done
#pragma unroll
    for (int i = 0; i < 4; i++) {
      load_lds16(ap0 + (size_t)i * 8 * K + k0, lA + i * 512);
      load_lds16(bp0 + (size_t)i * 8 * K + k0, lB + i * 512);
    }
    __syncthreads();  // implies vmcnt(0) drain of global_load_lds
#pragma unroll
    for (int ks = 0; ks < 2; ks++) {
      h8 af[4], bf[4];
      for (int mi = 0; mi < 4; mi++) {
        int r = wm + mi * 16 + l16;
        int pc = (ks * 4 + quad) ^ (l16 & 7);
        af[mi] = *(h8*)(&As[r * 64 + pc * 8]);
      }
      for (int ni = 0; ni < 4; ni++) {
        int r = wn + ni * 16 + l16;
        int pc = (ks * 4 + quad) ^ (l16 & 7);
        bf[ni] = *(h8*)(&Bs[r * 64 + pc * 8]);
      }
      for (int mi = 0; mi < 4; mi++)
        for (int ni = 0; ni < 4; ni++) acc[mi][ni] = MFMA16(af[mi], bf[ni], acc[mi][ni]);
    }
  }

  // Epilogue. C element (row = quad*4+r, col = l16) per 16x16 tile [m89-verified].
  for (int mi = 0; mi < 4; mi++)
    for (int ni = 0; ni < 4; ni++) {
      int gm_base = m0 + wm + mi * 16 + quad * 4;
      int gn = n0 + wn + ni * 16 + l16;
      float bv = bias[gn];
      for (int r = 0; r < 4; r++) {
        int gm = gm_base + r;
        float v = acc[mi][ni][r] + bv;
        if constexpr (MODE == 0) {
          int which = gn >> 11, h = (gn >> 7) & 15, d = gn & 127;
          int b = gm >> 11, s = gm & 2047;
          size_t hb = (size_t)b * 16 + h;
          if (which == 0)
            qp[(hb * 2048 + s) * 128 + d] = (_Float16)v;
          else if (which == 1)
            kp[(hb * 2048 + s) * 128 + d] = (_Float16)v;
          else
            vtp[(hb * 128 + d) * 2048 + s] = (_Float16)v;
        } else {
          outp[(size_t)gm * N + gn] = v;
        }
      }
    }
}

// ---------------- fused causal ALiBi attention (barrier-free, global fragments) ----------------
// grid (8, NH, B); block px handles 128-row q-tiles {15-px, px} (uniform ~34 iters/block).
// 4 independent waves, each owns 32 q-rows (2 MFMA row-sets). K/V fragments are read DIRECTLY
// from global in MFMA B-layout (K[j][d] and Vt[d][j] rows are contiguous h8) -- no staging LDS,
// no __syncthreads; waves run in near-lockstep so L1 (32 KB = one K+V tile) serves the reuse.
// LDS only for the per-wave P C-layout -> A-layout round-trip.
__global__ __launch_bounds__(256, 1) void attn_kernel(const _Float16* __restrict__ Q,
                                                      const _Float16* __restrict__ Kg,
                                                      const _Float16* __restrict__ Vt,
                                                      _Float16* __restrict__ ctx) {
  __shared__ _Float16 Pl[4][32][72];  // [wave][row][col], stride 144B (9x16B) conflict-free

  const int px = blockIdx.x, h = blockIdx.y, b = blockIdx.z;
  const int tid = threadIdx.x, w = tid >> 6, lane = tid & 63, quad = lane >> 4, l16 = lane & 15;
  const size_t hb = (size_t)b * 16 + h;
  const _Float16* Qh = Q + hb * (size_t)(2048 * 128);
  const _Float16* Kh = Kg + hb * (size_t)(2048 * 128);
  const _Float16* Vh = Vt + hb * (size_t)(2048 * 128);
  const float slope = exp2f(-0.5f * (float)h);
  const float L2E = 1.44269504088896f;
  const float NEG = -3.0e38f;

  for (int phase = 0; phase < 2; phase++) {
    const int t = phase ? px : 15 - px;
    const int qbase = t * 128 + w * 32;  // this wave's 32 q-rows (2 sets of 16)

    h8 aq[2][4];  // Q A-frags: A[m=l16][k=quad*8+j] [m120-verified]
    for (int s = 0; s < 2; s++)
      for (int t4 = 0; t4 < 4; t4++)
        aq[s][t4] = *(const h8*)(Qh + (size_t)(qbase + s * 16 + l16) * 128 + t4 * 32 + quad * 8);

    f4 o[2][8] = {};
    float m_i[2][4], l_i[2][4];
    for (int s = 0; s < 2; s++)
      for (int r = 0; r < 4; r++) { m_i[s][r] = NEG; l_i[s][r] = 0.f; }

    const int jtiles = (qbase + 95) >> 6;  // cover j <= qbase+31; per-wave trip count
    for (int jt = 0; jt < jtiles; jt++) {
      const int j0 = jt * 64;
      // S = Q K^T: B-frag B[n=l16->j][k=quad*8+r->d] = K[j][d], straight from global
      f4 sc[2][4] = {};
      for (int jf = 0; jf < 4; jf++) {
        h8 bk[4];
        for (int t4 = 0; t4 < 4; t4++)
          bk[t4] = *(const h8*)(Kh + (size_t)(j0 + jf * 16 + l16) * 128 + t4 * 32 + quad * 8);
        for (int t4 = 0; t4 < 4; t4++) {
          sc[0][jf] = MFMA16(aq[0][t4], bk[t4], sc[0][jf]);
          sc[1][jf] = MFMA16(aq[1][t4], bk[t4], sc[1][jf]);
        }
      }
      for (int s = 0; s < 2; s++) {
        // causal + alibi in C-layout (row=quad*4+r, col=l16)
        for (int jf = 0; jf < 4; jf++) {
          int j = j0 + jf * 16 + l16;
          for (int r = 0; r < 4; r++) {
            int i = qbase + s * 16 + quad * 4 + r;
            float sv = sc[s][jf][r];
            sc[s][jf][r] = (j <= i) ? (sv + slope * (float)(j - i)) : NEG;
          }
        }
        // online softmax: row stats across the 16-lane group
        float m_new[4], alpha[4];
        for (int r = 0; r < 4; r++) {
          float v = fmaxf(fmaxf(sc[s][0][r], sc[s][1][r]), fmaxf(sc[s][2][r], sc[s][3][r]));
          v = fmaxf(v, __shfl_xor(v, 1));
          v = fmaxf(v, __shfl_xor(v, 2));
          v = fmaxf(v, __shfl_xor(v, 4));
          v = fmaxf(v, __shfl_xor(v, 8));
          m_new[r] = fmaxf(m_i[s][r], v);
          alpha[r] = exp2f((m_i[s][r] - m_new[r]) * L2E);
        }
        for (int jf = 0; jf < 4; jf++)
          for (int r = 0; r < 4; r++) sc[s][jf][r] = exp2f((sc[s][jf][r] - m_new[r]) * L2E);
        for (int r = 0; r < 4; r++) {
          float sum = (sc[s][0][r] + sc[s][1][r]) + (sc[s][2][r] + sc[s][3][r]);
          sum += __shfl_xor(sum, 1);
          sum += __shfl_xor(sum, 2);
          sum += __shfl_xor(sum, 4);
          sum += __shfl_xor(sum, 8);
          l_i[s][r] = l_i[s][r] * alpha[r] + sum;
          m_i[s][r] = m_new[r];
        }
        for (int nt = 0; nt < 8; nt++)
          for (int r = 0; r < 4; r++) o[s][nt][r] *= alpha[r];
        // P: C-layout -> A-layout via per-wave LDS (wave-internal, DS in-order)
        for (int jf = 0; jf < 4; jf++)
          for (int r = 0; r < 4; r++)
            Pl[w][s * 16 + quad * 4 + r][jf * 16 + l16] = (_Float16)sc[s][jf][r];
      }
      asm volatile("s_waitcnt lgkmcnt(0)" ::: "memory");
      h8 ap[2][2];
      for (int s = 0; s < 2; s++)
        for (int hf = 0; hf < 2; hf++)
          ap[s][hf] = *(h8*)(&Pl[w][s * 16 + l16][hf * 32 + quad * 8]);
      // O += P V: B-frag B[n=l16->d][k=quad*8+r->j] = Vt[d][j], straight from global
      for (int nt = 0; nt < 8; nt++) {
        h8 bv0 = *(const h8*)(Vh + (size_t)(nt * 16 + l16) * 2048 + j0 + quad * 8);
        h8 bv1 = *(const h8*)(Vh + (size_t)(nt * 16 + l16) * 2048 + j0 + 32 + quad * 8);
        o[0][nt] = MFMA16(ap[0][0], bv0, o[0][nt]);
        o[0][nt] = MFMA16(ap[0][1], bv1, o[0][nt]);
        o[1][nt] = MFMA16(ap[1][0], bv0, o[1][nt]);
        o[1][nt] = MFMA16(ap[1][1], bv1, o[1][nt]);
      }
    }

    // epilogue: normalize, write ctx[b, s, h*128+d] (f16)
    for (int s = 0; s < 2; s++)
      for (int r = 0; r < 4; r++) {
        float inv = 1.0f / l_i[s][r];
        int i = qbase + s * 16 + quad * 4 + r;
        size_t row = (size_t)b * 2048 + i;
        for (int nt = 0; nt < 8; nt++)
          ctx[row * 2048 + h * 128 + nt * 16 + l16] = (_Float16)(o[s][nt][r] * inv);
      }
  }
}

extern "C" void kernel_launch(void* const* d_in, const int* in_sizes, int n_in, void* d_out,
                              int out_size, void* d_ws, size_t ws_size, hipStream_t stream) {
  const float* x = (const float*)d_in[0];      // [2,2048,2048]
  const float* qkv_w = (const float*)d_in[1];  // [2048,6144]
  const float* qkv_b = (const float*)d_in[2];  // [6144]
  const float* out_w = (const float*)d_in[3];  // [2048,2048]
  const float* out_b = (const float*)d_in[4];  // [2048]
  float* out = (float*)d_out;                  // [4096,2048] f32

  char* ws = (char*)d_ws;
  if (ws_size < 117440512u) return;  // need 112 MiB
  _Float16* xb  = (_Float16*)(ws + 0);          // 16 MiB  [4096][2048]
  _Float16* wqt = (_Float16*)(ws + 16777216);   // 24 MiB  [6144][2048]
  _Float16* wot = (_Float16*)(ws + 41943040);   // 8 MiB   [2048][2048]
  _Float16* q   = (_Float16*)(ws + 50331648);   // 16 MiB  [b,h,s,d]
  _Float16* k   = (_Float16*)(ws + 67108864);   // 16 MiB  [b,h,s,d]
  _Float16* vt  = (_Float16*)(ws + 83886080);   // 16 MiB  [b,h,d,s]
  _Float16* ctx = (_Float16*)(ws + 100663296);  // 16 MiB  [4096][2048]

  cvt_f32_f16<<<8192, 256, 0, stream>>>(x, xb, 8388608);
  transpose_cvt<<<dim3(96, 32), 256, 0, stream>>>(qkv_w, wqt, 2048, 6144);
  transpose_cvt<<<dim3(32, 32), 256, 0, stream>>>(out_w, wot, 2048, 2048);
  gemm_bt<0><<<dim3(48, 32), 256, 0, stream>>>(xb, wqt, qkv_b, 2048, q, k, vt, nullptr, 6144);
  attn_kernel<<<dim3(8, 16, 2), 256, 0, stream>>>(q, k, vt, ctx);
  gemm_bt<1><<<dim3(16, 32), 256, 0, stream>>>(ctx, wot, out_b, 2048, nullptr, nullptr, nullptr,
                                               out, 2048);
}

// Round 4
// 474.807 us; speedup vs baseline: 1.1435x; 1.1435x over previous
//
#include <hip/hip_runtime.h>

typedef _Float16 h8 __attribute__((ext_vector_type(8)));
typedef _Float16 h4 __attribute__((ext_vector_type(4)));
typedef float f4 __attribute__((ext_vector_type(4)));

#define MFMA16(a, b, c) __builtin_amdgcn_mfma_f32_16x16x32_f16((a), (b), (c), 0, 0, 0)
#define AS1 __attribute__((address_space(1)))
#define AS3 __attribute__((address_space(3)))

static __device__ __forceinline__ void load_lds16(const _Float16* g, _Float16* l) {
  // 16B per lane, LDS dest = wave-uniform base + lane*16 [m97]
  __builtin_amdgcn_global_load_lds((const AS1 void*)g, (AS3 void*)l, 16, 0, 0);
}

// ---------------- fp32 -> fp16 elementwise convert ----------------
__global__ __launch_bounds__(256) void cvt_f32_f16(const float* __restrict__ in,
                                                   _Float16* __restrict__ out, int n) {
  int i = (blockIdx.x * 256 + threadIdx.x) * 4;
  if (i < n) {
    const float4 v = *(const float4*)(in + i);
    h4 o;
    o[0] = (_Float16)v.x; o[1] = (_Float16)v.y; o[2] = (_Float16)v.z; o[3] = (_Float16)v.w;
    *(h4*)(out + i) = o;
  }
}

// ---------------- transpose+convert: W[K][N] f32 -> Wt[N][K] f16 ----------------
__global__ __launch_bounds__(256) void transpose_cvt(const float* __restrict__ W,
                                                     _Float16* __restrict__ Wt, int K, int N) {
  __shared__ _Float16 t[64][66];
  int n0 = blockIdx.x * 64, k0 = blockIdx.y * 64;
  int c = threadIdx.x & 63, r0 = threadIdx.x >> 6;
  for (int i = 0; i < 16; i++) {
    int r = r0 * 16 + i;
    t[r][c] = (_Float16)W[(size_t)(k0 + r) * N + n0 + c];
  }
  __syncthreads();
  for (int i = 0; i < 16; i++) {
    int r = r0 * 16 + i;
    Wt[(size_t)(n0 + r) * K + k0 + c] = t[c][r];
  }
}

// ---------------- GEMM (BK=64): C[M][N] = A[M][K] @ Bt[N][K]^T + bias ----------------
// K-loop: global_load_lds width=16 into unpadded BK=64 LDS, XOR chunk swizzle, 0 conflicts,
// 32 MFMA/barrier. MODE 0 epilogue: LDS-bounce (reusing the staging LDS) -> coalesced
// dwordx4 stores into q[b,h,s,d] / k[b,h,s,d] / vt[b,h,d,s] (V transposed in LDS).
// MODE 1: direct fp32 stores.
template <int MODE>
__global__ __launch_bounds__(256) void gemm_bt(const _Float16* __restrict__ A,
                                               const _Float16* __restrict__ Bt,
                                               const float* __restrict__ bias, int K,
                                               _Float16* __restrict__ qp, _Float16* __restrict__ kp,
                                               _Float16* __restrict__ vtp, float* __restrict__ outp,
                                               int N) {
  __shared__ _Float16 U[17408];  // 34.8 KB: K-loop uses [0,16384); epilogue uses all (128x136)
  _Float16* As = U;
  _Float16* Bs = U + 8192;
  const int m0 = blockIdx.y * 128, n0 = blockIdx.x * 128;
  const int tid = threadIdx.x;
  const int w = tid >> 6, lane = tid & 63, quad = lane >> 4, l16 = lane & 15;
  const int wm = (w >> 1) * 64, wn = (w & 1) * 64;

  const int lc8 = (((lane & 7) ^ (lane >> 3)) * 8);  // swizzled k-offset (elements)
  const int rb = w * 32 + (lane >> 3);               // staging row for call i: rb + i*8
  const _Float16* ap0 = A + (size_t)(m0 + rb) * K + lc8;
  const _Float16* bp0 = Bt + (size_t)(n0 + rb) * K + lc8;
  _Float16* lA = As + w * 2048;
  _Float16* lB = Bs + w * 2048;

  f4 acc[4][4] = {};
  for (int k0 = 0; k0 < K; k0 += 64) {
    __syncthreads();
#pragma unroll
    for (int i = 0; i < 4; i++) {
      load_lds16(ap0 + (size_t)i * 8 * K + k0, lA + i * 512);
      load_lds16(bp0 + (size_t)i * 8 * K + k0, lB + i * 512);
    }
    __syncthreads();  // implies vmcnt(0) drain
#pragma unroll
    for (int ks = 0; ks < 2; ks++) {
      h8 af[4], bf[4];
      for (int mi = 0; mi < 4; mi++) {
        int r = wm + mi * 16 + l16;
        int pc = (ks * 4 + quad) ^ (l16 & 7);
        af[mi] = *(h8*)(&As[r * 64 + pc * 8]);
      }
      for (int ni = 0; ni < 4; ni++) {
        int r = wn + ni * 16 + l16;
        int pc = (ks * 4 + quad) ^ (l16 & 7);
        bf[ni] = *(h8*)(&Bs[r * 64 + pc * 8]);
      }
      for (int mi = 0; mi < 4; mi++)
        for (int ni = 0; ni < 4; ni++) acc[mi][ni] = MFMA16(af[mi], bf[ni], acc[mi][ni]);
    }
  }

  // ---- Epilogue. C element (row = quad*4+r, col = l16) per 16x16 tile [m89-verified]. ----
  if constexpr (MODE == 0) {
    __syncthreads();  // K-loop fragment reads done before LDS reuse
    const int which = n0 >> 11;        // block-uniform (n-span 128)
    const int hh = (n0 >> 7) & 15;     // block-uniform head
    const int bq = m0 >> 11;           // batch (m0 128-aligned)
    const int ms = m0 & 2047;          // seq offset within batch
    const size_t hb = (size_t)bq * 16 + hh;
    if (which == 2) {
      // store transposed tile E[d][s], stride 136
      for (int mi = 0; mi < 4; mi++)
        for (int ni = 0; ni < 4; ni++) {
          int d = wn + ni * 16 + l16;
          int s0 = wm + mi * 16 + quad * 4;
          float bv = bias[n0 + d];
          h4 pack;
          for (int r = 0; r < 4; r++) pack[r] = (_Float16)(acc[mi][ni][r] + bv);
          *(h4*)(&U[d * 136 + s0]) = pack;
        }
    } else {
      // store tile E[s][d], stride 136
      for (int mi = 0; mi < 4; mi++)
        for (int ni = 0; ni < 4; ni++) {
          int d = wn + ni * 16 + l16;
          float bv = bias[n0 + d];
          for (int r = 0; r < 4; r++) {
            int s = wm + mi * 16 + quad * 4 + r;
            U[s * 136 + d] = (_Float16)(acc[mi][ni][r] + bv);
          }
        }
    }
    __syncthreads();
    if (which == 2) {
      _Float16* dst = vtp + hb * (size_t)(128 * 2048) + ms;  // row d (stride 2048), col s
#pragma unroll
      for (int i = 0; i < 8; i++) {
        int f = i * 256 + tid, row = f >> 4, ch = f & 15;
        *(h8*)(dst + (size_t)row * 2048 + ch * 8) = *(h8*)(&U[row * 136 + ch * 8]);
      }
    } else {
      _Float16* dst = (which == 0 ? qp : kp) + (hb * 2048 + ms) * (size_t)128;
#pragma unroll
      for (int i = 0; i < 8; i++) {
        int f = i * 256 + tid, row = f >> 4, ch = f & 15;
        *(h8*)(dst + (size_t)row * 128 + ch * 8) = *(h8*)(&U[row * 136 + ch * 8]);
      }
    }
  } else {
    for (int mi = 0; mi < 4; mi++)
      for (int ni = 0; ni < 4; ni++) {
        int gm_base = m0 + wm + mi * 16 + quad * 4;
        int gn = n0 + wn + ni * 16 + l16;
        float bv = bias[gn];
        for (int r = 0; r < 4; r++)
          outp[(size_t)(gm_base + r) * N + gn] = acc[mi][ni][r] + bv;
      }
  }
}

// ---------------- fused causal ALiBi attention (LDS-staged, 32 q-rows/wave) ----------------
// grid (8, NH, B); block px handles 128-row q-tiles {15-px, px} -> uniform 34 j-iters.
// 4 waves x 32 q-rows (2 row-sets sharing every K/V fragment read -> 2x FLOP per LDS byte
// vs r2). j-tile 64; next K/V tile prefetched into VGPRs while current computes.
__global__ __launch_bounds__(256, 1) void attn_kernel(const _Float16* __restrict__ Q,
                                                      const _Float16* __restrict__ Kg,
                                                      const _Float16* __restrict__ Vt,
                                                      _Float16* __restrict__ ctx) {
  __shared__ _Float16 Ks[64][136];    // [j][d]
  __shared__ _Float16 Vs[128][72];    // [d][j]
  __shared__ _Float16 Pl[4][32][72];  // per-wave P round-trip (C-layout -> A-layout)

  const int px = blockIdx.x, h = blockIdx.y, b = blockIdx.z;
  const int tid = threadIdx.x, w = tid >> 6, lane = tid & 63, quad = lane >> 4, l16 = lane & 15;
  const size_t hb = (size_t)b * 16 + h;
  const _Float16* Qh = Q + hb * (size_t)(2048 * 128);
  const _Float16* Kh = Kg + hb * (size_t)(2048 * 128);
  const _Float16* Vh = Vt + hb * (size_t)(2048 * 128);
  const float slope = exp2f(-0.5f * (float)h);
  const float L2E = 1.44269504088896f;
  const float NEG = -3.0e38f;

  for (int phase = 0; phase < 2; phase++) {
    const int t = phase ? px : 15 - px;
    const int qbase = t * 128 + w * 32;  // wave's 32 q-rows (2 sets of 16)

    h8 aq[2][4];  // Q A-frags: A[m=l16][k=quad*8+j] [m120-verified]
    for (int s = 0; s < 2; s++)
      for (int t4 = 0; t4 < 4; t4++)
        aq[s][t4] = *(const h8*)(Qh + (size_t)(qbase + s * 16 + l16) * 128 + t4 * 32 + quad * 8);

    f4 o[2][8] = {};
    float m_i[2][4], l_i[2][4];
    for (int s = 0; s < 2; s++)
      for (int r = 0; r < 4; r++) { m_i[s][r] = NEG; l_i[s][r] = 0.f; }

    const int jtiles = 2 * t + 2;  // block-uniform
    // prefetch tile 0
    h8 pk[4], pv[4];
    for (int i = 0; i < 4; i++) {
      int id = tid + 256 * i;
      pk[i] = *(const h8*)(Kh + (size_t)(id >> 4) * 128 + (id & 15) * 8);
      pv[i] = *(const h8*)(Vh + (size_t)(id >> 3) * 2048 + (id & 7) * 8);
    }

    for (int jt = 0; jt < jtiles; jt++) {
      const int j0 = jt * 64;
      __syncthreads();  // previous tile's LDS readers done
      for (int i = 0; i < 4; i++) {
        int id = tid + 256 * i;
        *(h8*)(&Ks[id >> 4][(id & 15) * 8]) = pk[i];
        *(h8*)(&Vs[id >> 3][(id & 7) * 8]) = pv[i];
      }
      __syncthreads();
      if (jt + 1 < jtiles) {  // prefetch next tile; latency overlaps compute below
        int jn = j0 + 64;
        for (int i = 0; i < 4; i++) {
          int id = tid + 256 * i;
          pk[i] = *(const h8*)(Kh + (size_t)(jn + (id >> 4)) * 128 + (id & 15) * 8);
          pv[i] = *(const h8*)(Vh + (size_t)(id >> 3) * 2048 + jn + (id & 7) * 8);
        }
      }
      if (j0 > qbase + 31) continue;  // wave fully masked (still hits both barriers)

      // S = Q K^T : 2 row-sets x 4 j-frags; each B-frag read feeds both row-sets
      f4 sc[2][4] = {};
      for (int jf = 0; jf < 4; jf++)
        for (int t4 = 0; t4 < 4; t4++) {
          h8 bk = *(h8*)(&Ks[jf * 16 + l16][t4 * 32 + quad * 8]);
          sc[0][jf] = MFMA16(aq[0][t4], bk, sc[0][jf]);
          sc[1][jf] = MFMA16(aq[1][t4], bk, sc[1][jf]);
        }
      for (int s = 0; s < 2; s++) {
        // causal + alibi in C-layout (row=quad*4+r, col=l16)
        for (int jf = 0; jf < 4; jf++) {
          int j = j0 + jf * 16 + l16;
          for (int r = 0; r < 4; r++) {
            int i = qbase + s * 16 + quad * 4 + r;
            float sv = sc[s][jf][r];
            sc[s][jf][r] = (j <= i) ? (sv + slope * (float)(j - i)) : NEG;
          }
        }
        // online softmax: row stats across the 16-lane group
        float m_new[4], alpha[4];
        for (int r = 0; r < 4; r++) {
          float v = fmaxf(fmaxf(sc[s][0][r], sc[s][1][r]), fmaxf(sc[s][2][r], sc[s][3][r]));
          v = fmaxf(v, __shfl_xor(v, 1));
          v = fmaxf(v, __shfl_xor(v, 2));
          v = fmaxf(v, __shfl_xor(v, 4));
          v = fmaxf(v, __shfl_xor(v, 8));
          m_new[r] = fmaxf(m_i[s][r], v);
          alpha[r] = exp2f((m_i[s][r] - m_new[r]) * L2E);
        }
        for (int jf = 0; jf < 4; jf++)
          for (int r = 0; r < 4; r++) sc[s][jf][r] = exp2f((sc[s][jf][r] - m_new[r]) * L2E);
        for (int r = 0; r < 4; r++) {
          float sum = (sc[s][0][r] + sc[s][1][r]) + (sc[s][2][r] + sc[s][3][r]);
          sum += __shfl_xor(sum, 1);
          sum += __shfl_xor(sum, 2);
          sum += __shfl_xor(sum, 4);
          sum += __shfl_xor(sum, 8);
          l_i[s][r] = l_i[s][r] * alpha[r] + sum;
          m_i[s][r] = m_new[r];
        }
        for (int nt = 0; nt < 8; nt++)
          for (int r = 0; r < 4; r++) o[s][nt][r] *= alpha[r];
        // P: C-layout -> A-layout via per-wave LDS (wave-internal, DS in-order)
        for (int jf = 0; jf < 4; jf++)
          for (int r = 0; r < 4; r++)
            Pl[w][s * 16 + quad * 4 + r][jf * 16 + l16] = (_Float16)sc[s][jf][r];
      }
      asm volatile("s_waitcnt lgkmcnt(0)" ::: "memory");
      h8 ap[2][2];
      for (int s = 0; s < 2; s++)
        for (int hf = 0; hf < 2; hf++)
          ap[s][hf] = *(h8*)(&Pl[w][s * 16 + l16][hf * 32 + quad * 8]);
      // O += P V : 8 n-tiles over D=128; each V-frag read feeds both row-sets
      for (int nt = 0; nt < 8; nt++) {
        h8 bv0 = *(h8*)(&Vs[nt * 16 + l16][quad * 8]);
        h8 bv1 = *(h8*)(&Vs[nt * 16 + l16][32 + quad * 8]);
        o[0][nt] = MFMA16(ap[0][0], bv0, o[0][nt]);
        o[0][nt] = MFMA16(ap[0][1], bv1, o[0][nt]);
        o[1][nt] = MFMA16(ap[1][0], bv0, o[1][nt]);
        o[1][nt] = MFMA16(ap[1][1], bv1, o[1][nt]);
      }
    }

    // epilogue: normalize, write ctx[b, s, h*128+d] (f16)
    for (int s = 0; s < 2; s++)
      for (int r = 0; r < 4; r++) {
        float inv = 1.0f / l_i[s][r];
        int i = qbase + s * 16 + quad * 4 + r;
        size_t row = (size_t)b * 2048 + i;
        for (int nt = 0; nt < 8; nt++)
          ctx[row * 2048 + h * 128 + nt * 16 + l16] = (_Float16)(o[s][nt][r] * inv);
      }
  }
}

extern "C" void kernel_launch(void* const* d_in, const int* in_sizes, int n_in, void* d_out,
                              int out_size, void* d_ws, size_t ws_size, hipStream_t stream) {
  const float* x = (const float*)d_in[0];      // [2,2048,2048]
  const float* qkv_w = (const float*)d_in[1];  // [2048,6144]
  const float* qkv_b = (const float*)d_in[2];  // [6144]
  const float* out_w = (const float*)d_in[3];  // [2048,2048]
  const float* out_b = (const float*)d_in[4];  // [2048]
  float* out = (float*)d_out;                  // [4096,2048] f32

  char* ws = (char*)d_ws;
  if (ws_size < 117440512u) return;  // need 112 MiB
  _Float16* xb  = (_Float16*)(ws + 0);          // 16 MiB  [4096][2048]
  _Float16* wqt = (_Float16*)(ws + 16777216);   // 24 MiB  [6144][2048]
  _Float16* wot = (_Float16*)(ws + 41943040);   // 8 MiB   [2048][2048]
  _Float16* q   = (_Float16*)(ws + 50331648);   // 16 MiB  [b,h,s,d]
  _Float16* k   = (_Float16*)(ws + 67108864);   // 16 MiB  [b,h,s,d]
  _Float16* vt  = (_Float16*)(ws + 83886080);   // 16 MiB  [b,h,d,s]
  _Float16* ctx = (_Float16*)(ws + 100663296);  // 16 MiB  [4096][2048]

  cvt_f32_f16<<<8192, 256, 0, stream>>>(x, xb, 8388608);
  transpose_cvt<<<dim3(96, 32), 256, 0, stream>>>(qkv_w, wqt, 2048, 6144);
  transpose_cvt<<<dim3(32, 32), 256, 0, stream>>>(out_w, wot, 2048, 2048);
  gemm_bt<0><<<dim3(48, 32), 256, 0, stream>>>(xb, wqt, qkv_b, 2048, q, k, vt, nullptr, 6144);
  attn_kernel<<<dim3(8, 16, 2), 256, 0, stream>>>(q, k, vt, ctx);
  gemm_bt<1><<<dim3(16, 32), 256, 0, stream>>>(ctx, wot, out_b, 2048, nullptr, nullptr, nullptr,
                                               out, 2048);
}

// Round 5
// 370.920 us; speedup vs baseline: 1.4638x; 1.2801x over previous
//
#include <hip/hip_runtime.h>

typedef _Float16 h8 __attribute__((ext_vector_type(8)));
typedef _Float16 h4 __attribute__((ext_vector_type(4)));
typedef float f4 __attribute__((ext_vector_type(4)));

#define MFMA16(a, b, c) __builtin_amdgcn_mfma_f32_16x16x32_f16((a), (b), (c), 0, 0, 0)
#define AS1 __attribute__((address_space(1)))
#define AS3 __attribute__((address_space(3)))

static __device__ __forceinline__ void load_lds16(const _Float16* g, _Float16* l) {
  // async DMA: 16B per lane, LDS dest = wave-uniform base + lane*16 [m97]
  __builtin_amdgcn_global_load_lds((const AS1 void*)g, (AS3 void*)l, 16, 0, 0);
}

// ---------------- fp32 -> fp16 elementwise convert ----------------
__global__ __launch_bounds__(256) void cvt_f32_f16(const float* __restrict__ in,
                                                   _Float16* __restrict__ out, int n) {
  int i = (blockIdx.x * 256 + threadIdx.x) * 4;
  if (i < n) {
    const float4 v = *(const float4*)(in + i);
    h4 o;
    o[0] = (_Float16)v.x; o[1] = (_Float16)v.y; o[2] = (_Float16)v.z; o[3] = (_Float16)v.w;
    *(h4*)(out + i) = o;
  }
}

// ---------------- transpose+convert: W[K][N] f32 -> Wt[N][K] f16 ----------------
__global__ __launch_bounds__(256) void transpose_cvt(const float* __restrict__ W,
                                                     _Float16* __restrict__ Wt, int K, int N) {
  __shared__ _Float16 t[64][66];
  int n0 = blockIdx.x * 64, k0 = blockIdx.y * 64;
  int c = threadIdx.x & 63, r0 = threadIdx.x >> 6;
  for (int i = 0; i < 16; i++) {
    int r = r0 * 16 + i;
    t[r][c] = (_Float16)W[(size_t)(k0 + r) * N + n0 + c];
  }
  __syncthreads();
  for (int i = 0; i < 16; i++) {
    int r = r0 * 16 + i;
    Wt[(size_t)(n0 + r) * K + k0 + c] = t[c][r];
  }
}

// ---------------- GEMM (BK=64, async double-buffered): C = A @ Bt^T + bias ----------------
// Single barrier per K-iter: DMA for tile k+1 issued right after the barrier into the back
// buffer; its latency is hidden by tile k's 32 MFMAs; the drain lands at the NEXT barrier.
// XOR chunk swizzle (proven 0 conflicts in r2-r4). MODE 0: QKV scatter epilogue via LDS
// bounce; MODE 1: fp32 out.
template <int MODE>
__global__ __launch_bounds__(256, 2) void gemm_bt(const _Float16* __restrict__ A,
                                               const _Float16* __restrict__ Bt,
                                               const float* __restrict__ bias, int K,
                                               _Float16* __restrict__ qp, _Float16* __restrict__ kp,
                                               _Float16* __restrict__ vtp, float* __restrict__ outp,
                                               int N) {
  __shared__ _Float16 LDS[2][16384];  // [buf][ As 8192 | Bs 8192 ], 64 KB total
  const int m0 = blockIdx.y * 128, n0 = blockIdx.x * 128;
  const int tid = threadIdx.x;
  const int w = tid >> 6, lane = tid & 63, quad = lane >> 4, l16 = lane & 15;
  const int wm = (w >> 1) * 64, wn = (w & 1) * 64;

  const int lc8 = (((lane & 7) ^ (lane >> 3)) * 8);  // swizzled k-offset (f16)
  const int rb = w * 32 + (lane >> 3);
  const _Float16* ap0 = A + (size_t)(m0 + rb) * K + lc8;
  const _Float16* bp0 = Bt + (size_t)(n0 + rb) * K + lc8;

  f4 acc[4][4] = {};
  // prologue: stage k=0 into buf 0
#pragma unroll
  for (int i = 0; i < 4; i++) {
    load_lds16(ap0 + (size_t)(i * 8) * K, &LDS[0][w * 2048 + i * 512]);
    load_lds16(bp0 + (size_t)(i * 8) * K, &LDS[0][8192 + w * 2048 + i * 512]);
  }
  for (int k0 = 0; k0 < K; k0 += 64) {
    const int cur = (k0 >> 6) & 1;
    __syncthreads();  // buf[cur] DMA drained (all waves) + prev readers of buf[cur^1] done
    if (k0 + 64 < K) {
      const int nb = cur ^ 1;
#pragma unroll
      for (int i = 0; i < 4; i++) {
        load_lds16(ap0 + (size_t)(i * 8) * K + k0 + 64, &LDS[nb][w * 2048 + i * 512]);
        load_lds16(bp0 + (size_t)(i * 8) * K + k0 + 64, &LDS[nb][8192 + w * 2048 + i * 512]);
      }
    }
    const _Float16* As = &LDS[cur][0];
    const _Float16* Bs = &LDS[cur][8192];
#pragma unroll
    for (int ks = 0; ks < 2; ks++) {
      h8 af[4], bf[4];
      for (int mi = 0; mi < 4; mi++) {
        int r = wm + mi * 16 + l16;
        int pc = (ks * 4 + quad) ^ (l16 & 7);
        af[mi] = *(const h8*)(&As[r * 64 + pc * 8]);
      }
      for (int ni = 0; ni < 4; ni++) {
        int r = wn + ni * 16 + l16;
        int pc = (ks * 4 + quad) ^ (l16 & 7);
        bf[ni] = *(const h8*)(&Bs[r * 64 + pc * 8]);
      }
      for (int mi = 0; mi < 4; mi++)
        for (int ni = 0; ni < 4; ni++) acc[mi][ni] = MFMA16(af[mi], bf[ni], acc[mi][ni]);
    }
  }

  // ---- Epilogue. C element (row = quad*4+r, col = l16) per 16x16 tile [m89-verified]. ----
  if constexpr (MODE == 0) {
    __syncthreads();
    _Float16* U = &LDS[0][0];  // 128 x 136 bounce tile (34816 B <= 64 KB)
    const int which = n0 >> 11, hh = (n0 >> 7) & 15;
    const int bq = m0 >> 11, ms = m0 & 2047;
    const size_t hb = (size_t)bq * 16 + hh;
    if (which == 2) {
      for (int mi = 0; mi < 4; mi++)
        for (int ni = 0; ni < 4; ni++) {
          int d = wn + ni * 16 + l16;
          int s0 = wm + mi * 16 + quad * 4;
          float bv = bias[n0 + d];
          h4 pack;
          for (int r = 0; r < 4; r++) pack[r] = (_Float16)(acc[mi][ni][r] + bv);
          *(h4*)(&U[d * 136 + s0]) = pack;
        }
    } else {
      for (int mi = 0; mi < 4; mi++)
        for (int ni = 0; ni < 4; ni++) {
          int d = wn + ni * 16 + l16;
          float bv = bias[n0 + d];
          for (int r = 0; r < 4; r++) {
            int s = wm + mi * 16 + quad * 4 + r;
            U[s * 136 + d] = (_Float16)(acc[mi][ni][r] + bv);
          }
        }
    }
    __syncthreads();
    if (which == 2) {
      _Float16* dst = vtp + hb * (size_t)(128 * 2048) + ms;
#pragma unroll
      for (int i = 0; i < 8; i++) {
        int f = i * 256 + tid, row = f >> 4, ch = f & 15;
        *(h8*)(dst + (size_t)row * 2048 + ch * 8) = *(h8*)(&U[row * 136 + ch * 8]);
      }
    } else {
      _Float16* dst = (which == 0 ? qp : kp) + (hb * 2048 + ms) * (size_t)128;
#pragma unroll
      for (int i = 0; i < 8; i++) {
        int f = i * 256 + tid, row = f >> 4, ch = f & 15;
        *(h8*)(dst + (size_t)row * 128 + ch * 8) = *(h8*)(&U[row * 136 + ch * 8]);
      }
    }
  } else {
    for (int mi = 0; mi < 4; mi++)
      for (int ni = 0; ni < 4; ni++) {
        int gm_base = m0 + wm + mi * 16 + quad * 4;
        int gn = n0 + wn + ni * 16 + l16;
        float bv = bias[gn];
        for (int r = 0; r < 4; r++)
          outp[(size_t)(gm_base + r) * N + gn] = acc[mi][ni][r] + bv;
      }
  }
}

// ---------------- fused causal ALiBi attention ----------------
// grid (32 bh, 16 px): 512 uniform blocks (2/CU, 2 waves/SIMD); same-(b,h) blocks share an
// XCD (linear id mod 8 = bh mod 8) so K/V re-reads hit that XCD's L2.
// Block: 4 waves x 16 q-rows = 64-row tile; pairs {31-px, px} -> 33 j-iters each.
// K/V async-DMA double-buffered (1 barrier/iter, latency hidden under compute).
// ALiBi as column bias slope*j (row term -slope*i cancels in softmax); causal mask only on
// the diagonal tile. Row-sum l via a ones-column MFMA tile (o[8]).
__global__ __launch_bounds__(256, 2) void attn_kernel(const _Float16* __restrict__ Q,
                                                      const _Float16* __restrict__ Kg,
                                                      const _Float16* __restrict__ Vt,
                                                      _Float16* __restrict__ ctx) {
  __shared__ _Float16 Ks[2][8192];   // 64 rows x 128, 16B-chunk XOR swizzle p = lc ^ (row&7)
  __shared__ _Float16 Vs[2][8192];   // 128 rows x 64, same swizzle
  __shared__ _Float16 Vones[1088];   // [16][68]: row 0 = ones (l-accumulator B-tile)
  __shared__ _Float16 Pl[4][16 * 68];  // per-wave P round-trip; stride 68 -> conflict-free

  const int bh = blockIdx.x, px = blockIdx.y;
  const int b = bh >> 4, h = bh & 15;
  const int tid = threadIdx.x, w = tid >> 6, lane = tid & 63, quad = lane >> 4, l16 = lane & 15;
  const size_t hbo = (size_t)bh * (2048 * 128);
  const _Float16* Qh = Q + hbo;
  const _Float16* Kh = Kg + hbo;
  const _Float16* Vh = Vt + hbo;
  const float slope = exp2f(-0.5f * (float)h);
  const float L2E = 1.44269504088896f;
  const float NEG = -3.0e38f;

  for (int i = tid; i < 1088; i += 256) Vones[i] = (_Float16)0.f;
  if (tid < 64) Vones[tid] = (_Float16)1.f;  // row 0, cols 0..63

  float cj[4];
  for (int jf = 0; jf < 4; jf++) cj[jf] = slope * (float)(jf * 16 + l16);

  // staging constants: K slot s=c*64+lane -> row=4c+quad, lc=l16^((c&1)*4+quad)
  //                    V slot s=c*64+lane -> row=8c+(lane>>3), lc=(lane&7)^(lane>>3)
  const int kle = (l16 ^ quad) * 8, klo = kle ^ 32;
  const int lq = lane >> 3, vlc = ((lane & 7) ^ lq) * 8;

  for (int phase = 0; phase < 2; phase++) {
    const int t = phase ? px : 31 - px;
    const int qbase = t * 64 + w * 16;

    h8 aq[4];  // Q A-frags: A[m=l16][k=quad*8+j] [m120-verified]
#pragma unroll
    for (int t4 = 0; t4 < 4; t4++)
      aq[t4] = *(const h8*)(Qh + (size_t)(qbase + l16) * 128 + t4 * 32 + quad * 8);

    f4 o[9] = {};  // o[0..7] = output tiles, o[8] = row-sum (ones column)
    float m_i[4];
    for (int r = 0; r < 4; r++) m_i[r] = NEG;

    const int jtiles = t + 1;
    __syncthreads();  // previous phase's buffer readers (and Vones init) done
    // stage tile 0 -> buf 0 (waves 0,1: K; waves 2,3: V)
    if (w < 2) {
      const _Float16* kb = Kh + (size_t)(32 * w + quad) * 128;
      _Float16* dst = &Ks[0][w * 4096];
#pragma unroll
      for (int cc = 0; cc < 8; cc++)
        load_lds16(kb + (size_t)(4 * cc) * 128 + ((cc & 1) ? klo : kle), dst + cc * 512);
    } else {
      const _Float16* vb = Vh + (size_t)(64 * (w - 2) + lq) * 2048 + vlc;
      _Float16* dst = &Vs[0][(w - 2) * 4096];
#pragma unroll
      for (int cc = 0; cc < 8; cc++) load_lds16(vb + (size_t)(8 * cc) * 2048, dst + cc * 512);
    }

    for (int jt = 0; jt < jtiles; jt++) {
      const int j0 = jt * 64, cur = jt & 1;
      __syncthreads();  // buf[cur] staged (each wave drains vmcnt before barrier)
      if (jt + 1 < jtiles) {  // async-stage next tile into back buffer
        const int nj0 = j0 + 64, nb = cur ^ 1;
        if (w < 2) {
          const _Float16* kb = Kh + (size_t)(nj0 + 32 * w + quad) * 128;
          _Float16* dst = &Ks[nb][w * 4096];
#pragma unroll
          for (int cc = 0; cc < 8; cc++)
            load_lds16(kb + (size_t)(4 * cc) * 128 + ((cc & 1) ? klo : kle), dst + cc * 512);
        } else {
          const _Float16* vb = Vh + (size_t)(64 * (w - 2) + lq) * 2048 + nj0 + vlc;
          _Float16* dst = &Vs[nb][(w - 2) * 4096];
#pragma unroll
          for (int cc = 0; cc < 8; cc++) load_lds16(vb + (size_t)(8 * cc) * 2048, dst + cc * 512);
        }
      }
      // S = Q K^T (B-frag from swizzled Ks)
      f4 sc[4] = {};
#pragma unroll
      for (int jf = 0; jf < 4; jf++) {
        const int row = jf * 16 + l16;
#pragma unroll
        for (int t4 = 0; t4 < 4; t4++) {
          const int p = (t4 * 4 + quad) ^ (l16 & 7);
          h8 bk = *(const h8*)(&Ks[cur][row * 128 + p * 8]);
          sc[jf] = MFMA16(aq[t4], bk, sc[jf]);
        }
      }
      // ALiBi column bias
      const float bj0 = slope * (float)j0;
#pragma unroll
      for (int jf = 0; jf < 4; jf++) {
        const float cb = bj0 + cj[jf];
#pragma unroll
        for (int r = 0; r < 4; r++) sc[jf][r] += cb;
      }
      if (jt == jtiles - 1) {  // diagonal tile: causal mask
#pragma unroll
        for (int jf = 0; jf < 4; jf++) {
          const int j = j0 + jf * 16 + l16;
#pragma unroll
          for (int r = 0; r < 4; r++)
            if (j > qbase + quad * 4 + r) sc[jf][r] = NEG;
        }
      }
      // online softmax (max only; sum rides in o[8])
      float m_new[4], alpha[4];
#pragma unroll
      for (int r = 0; r < 4; r++) {
        float v = fmaxf(fmaxf(sc[0][r], sc[1][r]), fmaxf(sc[2][r], sc[3][r]));
        v = fmaxf(v, __shfl_xor(v, 1));
        v = fmaxf(v, __shfl_xor(v, 2));
        v = fmaxf(v, __shfl_xor(v, 4));
        v = fmaxf(v, __shfl_xor(v, 8));
        m_new[r] = fmaxf(m_i[r], v);
        alpha[r] = exp2f((m_i[r] - m_new[r]) * L2E);
        m_i[r] = m_new[r];
      }
#pragma unroll
      for (int jf = 0; jf < 4; jf++)
#pragma unroll
        for (int r = 0; r < 4; r++) sc[jf][r] = exp2f((sc[jf][r] - m_new[r]) * L2E);
#pragma unroll
      for (int nt = 0; nt < 9; nt++)
#pragma unroll
        for (int r = 0; r < 4; r++) o[nt][r] *= alpha[r];
      // P: C-layout -> A-layout via per-wave LDS (stride 68: conflict-free writes)
#pragma unroll
      for (int jf = 0; jf < 4; jf++)
#pragma unroll
        for (int r = 0; r < 4; r++)
          Pl[w][(quad * 4 + r) * 68 + jf * 16 + l16] = (_Float16)sc[jf][r];
      asm volatile("s_waitcnt lgkmcnt(0)" ::: "memory");
      h8 ap0 = *(const h8*)(&Pl[w][l16 * 68 + quad * 8]);
      h8 ap1 = *(const h8*)(&Pl[w][l16 * 68 + 32 + quad * 8]);
      // O += P V (B-frag from swizzled Vs) + ones-tile for l
#pragma unroll
      for (int nt = 0; nt < 8; nt++) {
        const int row = nt * 16 + l16;
        const int p0 = quad ^ (l16 & 7), p1 = (4 + quad) ^ (l16 & 7);
        h8 bv0 = *(const h8*)(&Vs[cur][row * 64 + p0 * 8]);
        h8 bv1 = *(const h8*)(&Vs[cur][row * 64 + p1 * 8]);
        o[nt] = MFMA16(ap0, bv0, o[nt]);
        o[nt] = MFMA16(ap1, bv1, o[nt]);
      }
      {
        h8 b0 = *(const h8*)(&Vones[l16 * 68 + quad * 8]);
        h8 b1 = *(const h8*)(&Vones[l16 * 68 + 32 + quad * 8]);
        o[8] = MFMA16(ap0, b0, o[8]);
        o[8] = MFMA16(ap1, b1, o[8]);
      }
    }

    // epilogue: l = o[8] col 0 (broadcast within quad), normalize, write ctx
#pragma unroll
    for (int r = 0; r < 4; r++) {
      float lsum = __shfl(o[8][r], lane & 48);
      float inv = 1.0f / lsum;
      const int i = qbase + quad * 4 + r;
      const size_t row = (size_t)b * 2048 + i;
#pragma unroll
      for (int nt = 0; nt < 8; nt++)
        ctx[row * 2048 + h * 128 + nt * 16 + l16] = (_Float16)(o[nt][r] * inv);
    }
  }
}

extern "C" void kernel_launch(void* const* d_in, const int* in_sizes, int n_in, void* d_out,
                              int out_size, void* d_ws, size_t ws_size, hipStream_t stream) {
  const float* x = (const float*)d_in[0];      // [2,2048,2048]
  const float* qkv_w = (const float*)d_in[1];  // [2048,6144]
  const float* qkv_b = (const float*)d_in[2];  // [6144]
  const float* out_w = (const float*)d_in[3];  // [2048,2048]
  const float* out_b = (const float*)d_in[4];  // [2048]
  float* out = (float*)d_out;                  // [4096,2048] f32

  char* ws = (char*)d_ws;
  if (ws_size < 117440512u) return;  // need 112 MiB
  _Float16* xb  = (_Float16*)(ws + 0);          // 16 MiB  [4096][2048]
  _Float16* wqt = (_Float16*)(ws + 16777216);   // 24 MiB  [6144][2048]
  _Float16* wot = (_Float16*)(ws + 41943040);   // 8 MiB   [2048][2048]
  _Float16* q   = (_Float16*)(ws + 50331648);   // 16 MiB  [b,h,s,d]
  _Float16* k   = (_Float16*)(ws + 67108864);   // 16 MiB  [b,h,s,d]
  _Float16* vt  = (_Float16*)(ws + 83886080);   // 16 MiB  [b,h,d,s]
  _Float16* ctx = (_Float16*)(ws + 100663296);  // 16 MiB  [4096][2048]

  cvt_f32_f16<<<8192, 256, 0, stream>>>(x, xb, 8388608);
  transpose_cvt<<<dim3(96, 32), 256, 0, stream>>>(qkv_w, wqt, 2048, 6144);
  transpose_cvt<<<dim3(32, 32), 256, 0, stream>>>(out_w, wot, 2048, 2048);
  gemm_bt<0><<<dim3(48, 32), 256, 0, stream>>>(xb, wqt, qkv_b, 2048, q, k, vt, nullptr, 6144);
  attn_kernel<<<dim3(32, 16), 256, 0, stream>>>(q, k, vt, ctx);
  gemm_bt<1><<<dim3(16, 32), 256, 0, stream>>>(ctx, wot, out_b, 2048, nullptr, nullptr, nullptr,
                                               out, 2048);
}